// Round 5
// baseline (302.561 us; speedup 1.0000x reference)
//
#include <hip/hip_runtime.h>

// Problem constants (match reference)
constexpr int   T_STEPS = 64;
constexpr int   NN      = 2048;
constexpr float DT_TAU  = 0.1f;    // DT * TAU_MEM_INV
constexpr float V_TH_C  = 1.0f;
constexpr float TRC     = 0.05f;   // DT * TAU_PRE_INV == DT * TAU_POST_INV
constexpr float ETA     = 1e-3f;   // ETA_PLUS == ETA_MINUS

// 256 blocks x 512 threads (cooperative, 1 block/CU). Block b owns neurons
// [8b, 8b+8); wave w owns neuron 8b+w (w-row in 32 VGPR/lane; v/tpo/isyn
// replicated across its 64 lanes). z/tp replicated per block, rebuilt each
// step from the published spike words; thread tid exclusively owns the
// float4 covering neurons [4*tid, 4*tid+4) of z_s/tp_s, with tp persistent
// in a REGISTER (tp4) and mirrored to LDS for phase C.
//
// Step k (round-5 = round-4 skeleton, conflict-free unpack):
//  a. (all waves) LIF from register isyn -> z; v,tpo in regs; lane0 writes
//     raster + ds-atomic arrive on word_s[par] (add (1<<24)|(z<<w)). The
//     8TH ARRIVER publishes ONE tagged u64 ((k+1)<<32|bits) to this block's
//     private 128B line (~50cy after the last wave's butterfly; round-2
//     result: private lines removed MALL queuing, 244->203; round-4 result:
//     early publish + fused poll, 203->181).
//  b. ALL 512 threads poll word tid>>1 (two lanes share one address ->
//     merged into the wave's 32-line request; per-line MALL load unchanged),
//     unpack nibble (tid&1)*4 -> z4, update register tp4, store BOTH at
//     stride-1 float4 index tid. Round-4's 2*tid layout was a 16-way LDS
//     bank conflict (SQ_LDS_BANK_CONFLICT 2.58M) -- stride-1 restores 0.
//     __syncthreads  (RAW: b-writes visible before C-reads)
//  c. fused STDP w-update (regs) + matvec; butterfly -> isyn in regs;
//     prefetch next x into a register.
//     __syncthreads  (WAR: all C-reads of z_s/tp_s complete before any
//                     poller's next b-write; also orders word_s reset (a)
//                     before the k+2 arrivals that reuse that parity slot)
//
// Both barriers are necessary (round-3 regression + unsound WAR chain when
// removed). Cross-block safety: message==data (bits ride in the tagged word,
// single 8B atomic); tags 1..64 never match 0x00/0xAA poison; parity
// double-buffer + publish gating chain (publish(k+2) transitively requires
// every block's pollers consumed tag k+1) -> '!=' spin never misses; no ws
// initialization needed.
constexpr int BLOCKS  = 256;
constexpr int THREADS = 512;
constexpr int ROWS_PER_BLOCK = NN / BLOCKS;   // 8 == waves per block
constexpr int CHUNKS = NN / 256;              // 8 float4 chunks per lane

__global__ __launch_bounds__(THREADS)
void snn_msg_kernel(const float* __restrict__ x,       // [T, N]
                    const float* __restrict__ w_in,    // [N, N] pristine (never written)
                    const float* __restrict__ tpre0,   // [N]
                    const float* __restrict__ tpost0,  // [N]
                    unsigned long long* __restrict__ zpub, // [2][BLOCKS*stride]
                    int stride,                        // u64 units between words
                    float*       __restrict__ out)     // [T, N] spikes
{
    const int bid  = blockIdx.x;
    const int tid  = threadIdx.x;
    const int wv   = tid >> 6;
    const int lane = tid & 63;
    const int row  = bid * ROWS_PER_BLOCK + wv;   // this wave's neuron / w row

    __shared__ __align__(16) float z_s[NN];       // replicated spike vector
    __shared__ __align__(16) float tp_s[NN];      // replicated pre-trace mirror
    __shared__ __align__(16) float x_s[T_STEPS * ROWS_PER_BLOCK]; // owned inputs
    __shared__ unsigned word_s[2];                // [parity] count<<24 | bits

    // tp persistent in registers: thread tid owns neurons [4*tid, 4*tid+4).
    float4 tp4 = ((const float4*)tpre0)[tid];

    // Stage ALL owned inputs x[t][8b..8b+8) into LDS once.
    x_s[tid] = x[(size_t)(tid >> 3) * NN + bid * ROWS_PER_BLOCK + (tid & 7)];

    if (tid < 2) word_s[tid] = 0u;

    // Own-neuron state, replicated across all 64 lanes.
    float v_own   = 0.0f;
    float tpo_own = tpost0[row];          // broadcast load

    // This wave's w row: chunk c holds w[row][(c*64+lane)*4 ..+3].
    const float4* wrow4 = (const float4*)(w_in + (size_t)row * NN);
    float4 wreg[CHUNKS];
    #pragma unroll
    for (int c = 0; c < CHUNKS; ++c) wreg[c] = wrow4[c * 64 + lane];

    float isyn = 0.0f;                    // w @ z carry, lives in registers
    float xk   = 0.0f;                    // prefetched input current
    __syncthreads();
    xk = x_s[wv];                         // x[0][row] (post-barrier: x_s ready)

    for (int k = 0; k < T_STEPS; ++k) {
        const int par = k & 1;

        // ---- a: LIF (all lanes redundantly); lane0 raster + arrive/publish ----
        float v = v_own + DT_TAU * ((0.0f - v_own) + isyn + xk);
        float z = (v - V_TH_C > 0.0f) ? 1.0f : 0.0f;
        v_own   = v * (1.0f - z);
        tpo_own = tpo_own + TRC * (-tpo_own + z);   // post-trace (post-update
                                                    // value feeds C, as in ref)
        if (lane == 0) {
            out[(size_t)k * NN + row] = z;          // fire-and-forget raster
            if (k + 1 < T_STEPS) {
                unsigned add = 0x01000000u | (z > 0.0f ? (1u << wv) : 0u);
                unsigned old = __hip_atomic_fetch_add(&word_s[par], add,
                                   __ATOMIC_RELAXED, __HIP_MEMORY_SCOPE_WORKGROUP);
                if ((old >> 24) == 7u) {            // 8th arriver publishes
                    unsigned bits = (old + add) & 0xFFu;
                    // reset for reuse at k+2; ordered before k+2 arrivals by
                    // the post-b and post-C barriers of iterations k and k+1.
                    __hip_atomic_store(&word_s[par], 0u,
                                       __ATOMIC_RELAXED, __HIP_MEMORY_SCOPE_WORKGROUP);
                    unsigned long long wrd =
                        ((unsigned long long)(unsigned)(k + 1) << 32) | bits;
                    __hip_atomic_store(&zpub[(size_t)(par * BLOCKS + bid) * stride],
                                       wrd, __ATOMIC_RELAXED,
                                       __HIP_MEMORY_SCOPE_AGENT);
                }
            }
        }
        if (k == T_STEPS - 1) break;   // raster[63] written; no exchange needed

        // ---- b: all 512 threads poll word tid>>1, unpack ONE float4 in place ----
        {
            const unsigned long long* p =
                &zpub[(size_t)(par * BLOCKS + (tid >> 1)) * stride];
            unsigned long long pv = __hip_atomic_load(p, __ATOMIC_RELAXED,
                                        __HIP_MEMORY_SCOPE_AGENT);
            while ((unsigned)(pv >> 32) != (unsigned)(k + 1)) {
                __builtin_amdgcn_s_sleep(1);   // ~64cy backoff
                pv = __hip_atomic_load(p, __ATOMIC_RELAXED,
                                       __HIP_MEMORY_SCOPE_AGENT);
            }
            const unsigned bits = (unsigned)pv >> ((tid & 1) * 4); // our nibble
            float4 z4;
            z4.x = (bits & 0x1u) ? 1.0f : 0.0f;
            z4.y = (bits & 0x2u) ? 1.0f : 0.0f;
            z4.z = (bits & 0x4u) ? 1.0f : 0.0f;
            z4.w = (bits & 0x8u) ? 1.0f : 0.0f;
            // identical per-element expression as always -> bit-exact
            tp4.x = tp4.x + TRC * (-tp4.x + z4.x);
            tp4.y = tp4.y + TRC * (-tp4.y + z4.y);
            tp4.z = tp4.z + TRC * (-tp4.z + z4.z);
            tp4.w = tp4.w + TRC * (-tp4.w + z4.w);
            ((float4*)z_s)[tid]  = z4;     // stride-1: conflict-free
            ((float4*)tp_s)[tid] = tp4;    // stride-1: conflict-free
        }
        __syncthreads();               // RAW: b-writes -> C-reads

        // ---- c: fused STDP w-update + matvec (bit-exact order: c=0..7, xyzw) ----
        // Do not refactor into FMA (rounding would drift w, can flip spikes).
        const float zi_own = z;        // own neuron's spike (== z_s[row])
        const float tpoi   = tpo_own;  // own neuron's post-trace
        xk = x_s[(k + 1) * ROWS_PER_BLOCK + wv];   // prefetch next input
        float acc = 0.0f;
        const float4* z4s  = (const float4*)z_s;
        const float4* tp4s = (const float4*)tp_s;
        #pragma unroll
        for (int c = 0; c < CHUNKS; ++c) {
            float4 zj = z4s[c * 64 + lane];
            float4 tj = tp4s[c * 64 + lane];
            float nw;
            nw = wreg[c].x + (ETA * (zi_own * tj.x) - ETA * (tpoi * zj.x));
            nw = fminf(fmaxf(nw, 0.0f), 1.0f); wreg[c].x = nw; acc += nw * zj.x;
            nw = wreg[c].y + (ETA * (zi_own * tj.y) - ETA * (tpoi * zj.y));
            nw = fminf(fmaxf(nw, 0.0f), 1.0f); wreg[c].y = nw; acc += nw * zj.y;
            nw = wreg[c].z + (ETA * (zi_own * tj.z) - ETA * (tpoi * zj.z));
            nw = fminf(fmaxf(nw, 0.0f), 1.0f); wreg[c].z = nw; acc += nw * zj.z;
            nw = wreg[c].w + (ETA * (zi_own * tj.w) - ETA * (tpoi * zj.w));
            nw = fminf(fmaxf(nw, 0.0f), 1.0f); wreg[c].w = nw; acc += nw * zj.w;
        }
        #pragma unroll
        for (int m = 32; m >= 1; m >>= 1) acc += __shfl_xor(acc, m, 64);
        isyn = acc;                    // i_syn for step k+1, in registers

        __syncthreads();               // WAR: C-reads -> next b-writes
    }
}

extern "C" void kernel_launch(void* const* d_in, const int* in_sizes, int n_in,
                              void* d_out, int out_size, void* d_ws, size_t ws_size,
                              hipStream_t stream) {
    const float* x     = (const float*)d_in[0];   // [T,N]
    const float* w_in  = (const float*)d_in[1];   // [N,N]
    const float* tpre  = (const float*)d_in[2];   // [N]
    const float* tpost = (const float*)d_in[3];   // [N]
    float*       out   = (float*)d_out;           // [T,N]

    unsigned long long* zpub = (unsigned long long*)d_ws;

    // Pad each published word to its own line if the workspace allows:
    // 128B stride (TCC line) needs 64KB, 64B needs 32KB, else packed (4KB).
    int stride;
    if      (ws_size >= (size_t)2 * BLOCKS * 16 * sizeof(unsigned long long)) stride = 16;
    else if (ws_size >= (size_t)2 * BLOCKS *  8 * sizeof(unsigned long long)) stride = 8;
    else                                                                      stride = 1;

    void* args[] = {(void*)&x, (void*)&w_in, (void*)&tpre, (void*)&tpost,
                    (void*)&zpub, (void*)&stride, (void*)&out};
    hipLaunchCooperativeKernel((void*)snn_msg_kernel,
                               dim3(BLOCKS), dim3(THREADS),
                               args, 0, stream);
}

// Round 6
// 262.192 us; speedup vs baseline: 1.1540x; 1.1540x over previous
//
#include <hip/hip_runtime.h>

// Problem constants (match reference)
constexpr int   T_STEPS = 64;
constexpr int   NN      = 2048;
constexpr float DT_TAU  = 0.1f;    // DT * TAU_MEM_INV
constexpr float V_TH_C  = 1.0f;
constexpr float TRC     = 0.05f;   // DT * TAU_PRE_INV == DT * TAU_POST_INV
constexpr float ETA     = 1e-3f;   // ETA_PLUS == ETA_MINUS

// 256 blocks x 512 threads (cooperative, 1 block/CU). Block b owns neurons
// [8b, 8b+8); wave w owns neuron 8b+w (w-row in 32 VGPR/lane; v/tpo/isyn
// replicated across its 64 lanes). z/tp replicated per block in LDS, rebuilt
// each step from the published spike words.
//
// HARD-WON EXCHANGE RULES (rounds 1/2/4/5):
//  - Each block's published word on a PRIVATE 128B line (r2: 244->203; packed
//    lines saturate MALL line queues, publish stores queue behind polls).
//  - EXACTLY 256 pollers/block, one word each (r5: 512 pollers -> per-line
//    requesters double -> 181->217 regression. Agent-scope atomic loads issue
//    PER LANE; same-address lanes do NOT merge into one request).
//  - Publish by the 8TH ARRIVER via LDS atomic (r4: 203->181; fires ~50cy
//    after the last wave's butterfly, no barrier/wave-0 wakeup on the path).
//
// LDS LAYOUT (round-6 fix of round-4's 2.58M bank conflicts): SPLIT SLOTS.
// Poller tid unpacks word tid (neurons [8tid,8tid+8)) in place, storing
// float4 slot tid     = neurons [8tid, 8tid+4)
// float4 slot tid+256 = neurons [8tid+4, 8tid+8)
// -> both store instructions are stride-1 across the wave (conflict-free),
// unlike r4's slots {2tid, 2tid+1} (stride-2 = 8/16-way conflict).
// Phase C reads old float4 index i = c*64+lane at slot (i>>1) + 256*(i&1)
//   = c*32 + perm_base,  perm_base = (lane>>1) + 256*(lane&1)  (per-lane
// constant) -> two 512B stride-1 runs per read instruction: conflict-free,
// same values/order as ever -> bit-exact.
//
// Step k:
//  a. LIF from register isyn -> z; v,tpo in regs; lane0: raster store +
//     ds-atomic arrive on word_s[par] (add (1<<24)|(z<<wv)); 8th arriver
//     publishes ONE tagged u64 ((k+1)<<32|bits) to this block's line.
//  b. pollers tid<256 spin on word tid (tag k+1), unpack 8 neurons straight
//     into z_s split-slots; tp for those 8 neurons is PERSISTENT IN POLLER
//     REGISTERS (tpA/tpB), updated then mirrored to tp_s split-slots.
//     __syncthreads  (RAW: b-writes visible before C-reads)
//  c. fused STDP w-update (regs) + matvec (permuted slot reads); butterfly
//     -> isyn in regs; prefetch next x.
//     __syncthreads  (WAR: C-reads done before next b-writes; also orders
//                     word_s reset (a) before k+2 arrivals on that parity)
//
// Both barriers are necessary (r3: removal regressed + unsound WAR chain).
// Cross-block safety: message==data (bits ride in the tagged word, single 8B
// atomic); tags 1..64 never match 0x00/0xAA poison; parity double-buffer +
// publish gating chain (publish(k+2) transitively requires every block's
// pollers consumed tag k+1) -> '!=' spin never misses; no ws init needed.
constexpr int BLOCKS  = 256;
constexpr int THREADS = 512;
constexpr int ROWS_PER_BLOCK = NN / BLOCKS;   // 8 == waves per block
constexpr int CHUNKS = NN / 256;              // 8 float4 chunks per lane

__global__ __launch_bounds__(THREADS)
void snn_msg_kernel(const float* __restrict__ x,       // [T, N]
                    const float* __restrict__ w_in,    // [N, N] pristine (never written)
                    const float* __restrict__ tpre0,   // [N]
                    const float* __restrict__ tpost0,  // [N]
                    unsigned long long* __restrict__ zpub, // [2][BLOCKS*stride]
                    int stride,                        // u64 units between words
                    float*       __restrict__ out)     // [T, N] spikes
{
    const int bid  = blockIdx.x;
    const int tid  = threadIdx.x;
    const int wv   = tid >> 6;
    const int lane = tid & 63;
    const int row  = bid * ROWS_PER_BLOCK + wv;   // this wave's neuron / w row

    __shared__ __align__(16) float z_s[NN];       // spike vector (split-slot layout)
    __shared__ __align__(16) float tp_s[NN];      // pre-trace mirror (split-slot)
    __shared__ __align__(16) float x_s[T_STEPS * ROWS_PER_BLOCK]; // owned inputs
    __shared__ unsigned word_s[2];                // [parity] count<<24 | bits

    // Poller tid (<256) owns neurons [8tid, 8tid+8): tp persistent in regs.
    float4 tpA = make_float4(0.f, 0.f, 0.f, 0.f);
    float4 tpB = tpA;
    if (tid < BLOCKS) {
        tpA = ((const float4*)tpre0)[2 * tid];
        tpB = ((const float4*)tpre0)[2 * tid + 1];
    }

    // Stage ALL owned inputs x[t][8b..8b+8) into LDS once.
    x_s[tid] = x[(size_t)(tid >> 3) * NN + bid * ROWS_PER_BLOCK + (tid & 7)];

    if (tid < 2) word_s[tid] = 0u;

    // Own-neuron state, replicated across all 64 lanes.
    float v_own   = 0.0f;
    float tpo_own = tpost0[row];          // broadcast load

    // This wave's w row: chunk c holds w[row][(c*64+lane)*4 ..+3].
    const float4* wrow4 = (const float4*)(w_in + (size_t)row * NN);
    float4 wreg[CHUNKS];
    #pragma unroll
    for (int c = 0; c < CHUNKS; ++c) wreg[c] = wrow4[c * 64 + lane];

    // Per-lane constant base for the split-slot permutation (phase C reads).
    const int perm_base = (lane >> 1) + 256 * (lane & 1);

    float isyn = 0.0f;                    // w @ z carry, lives in registers
    float xk   = 0.0f;                    // prefetched input current
    __syncthreads();
    xk = x_s[wv];                         // x[0][row] (post-barrier: x_s ready)

    for (int k = 0; k < T_STEPS; ++k) {
        const int par = k & 1;

        // ---- a: LIF (all lanes redundantly); lane0 raster + arrive/publish ----
        float v = v_own + DT_TAU * ((0.0f - v_own) + isyn + xk);
        float z = (v - V_TH_C > 0.0f) ? 1.0f : 0.0f;
        v_own   = v * (1.0f - z);
        tpo_own = tpo_own + TRC * (-tpo_own + z);   // post-trace (post-update
                                                    // value feeds C, as in ref)
        if (lane == 0) {
            out[(size_t)k * NN + row] = z;          // fire-and-forget raster
            if (k + 1 < T_STEPS) {
                unsigned add = 0x01000000u | (z > 0.0f ? (1u << wv) : 0u);
                unsigned old = __hip_atomic_fetch_add(&word_s[par], add,
                                   __ATOMIC_RELAXED, __HIP_MEMORY_SCOPE_WORKGROUP);
                if ((old >> 24) == 7u) {            // 8th arriver publishes
                    unsigned bits = (old + add) & 0xFFu;
                    // reset for reuse at k+2; ordered before k+2 arrivals by
                    // the post-b and post-C barriers of iterations k and k+1.
                    __hip_atomic_store(&word_s[par], 0u,
                                       __ATOMIC_RELAXED, __HIP_MEMORY_SCOPE_WORKGROUP);
                    unsigned long long wrd =
                        ((unsigned long long)(unsigned)(k + 1) << 32) | bits;
                    __hip_atomic_store(&zpub[(size_t)(par * BLOCKS + bid) * stride],
                                       wrd, __ATOMIC_RELAXED,
                                       __HIP_MEMORY_SCOPE_AGENT);
                }
            }
        }
        if (k == T_STEPS - 1) break;   // raster[63] written; no exchange needed

        // ---- b: 256 pollers, one word each; in-place unpack to split slots ----
        if (tid < BLOCKS) {
            const unsigned long long* p =
                &zpub[(size_t)(par * BLOCKS + tid) * stride];
            unsigned long long pv = __hip_atomic_load(p, __ATOMIC_RELAXED,
                                        __HIP_MEMORY_SCOPE_AGENT);
            while ((unsigned)(pv >> 32) != (unsigned)(k + 1)) {
                __builtin_amdgcn_s_sleep(1);   // ~64cy backoff
                pv = __hip_atomic_load(p, __ATOMIC_RELAXED,
                                       __HIP_MEMORY_SCOPE_AGENT);
            }
            const unsigned bits = (unsigned)pv;   // z of neurons 8*tid..8*tid+7
            float4 zA, zB;
            zA.x = (bits & 0x01u) ? 1.0f : 0.0f;
            zA.y = (bits & 0x02u) ? 1.0f : 0.0f;
            zA.z = (bits & 0x04u) ? 1.0f : 0.0f;
            zA.w = (bits & 0x08u) ? 1.0f : 0.0f;
            zB.x = (bits & 0x10u) ? 1.0f : 0.0f;
            zB.y = (bits & 0x20u) ? 1.0f : 0.0f;
            zB.z = (bits & 0x40u) ? 1.0f : 0.0f;
            zB.w = (bits & 0x80u) ? 1.0f : 0.0f;
            // identical per-element expression as always -> bit-exact
            tpA.x = tpA.x + TRC * (-tpA.x + zA.x);
            tpA.y = tpA.y + TRC * (-tpA.y + zA.y);
            tpA.z = tpA.z + TRC * (-tpA.z + zA.z);
            tpA.w = tpA.w + TRC * (-tpA.w + zA.w);
            tpB.x = tpB.x + TRC * (-tpB.x + zB.x);
            tpB.y = tpB.y + TRC * (-tpB.y + zB.y);
            tpB.z = tpB.z + TRC * (-tpB.z + zB.z);
            tpB.w = tpB.w + TRC * (-tpB.w + zB.w);
            // split-slot stores: both instructions stride-1 across the wave
            ((float4*)z_s)[tid]          = zA;
            ((float4*)z_s)[tid + BLOCKS] = zB;
            ((float4*)tp_s)[tid]          = tpA;
            ((float4*)tp_s)[tid + BLOCKS] = tpB;
        }
        __syncthreads();               // RAW: b-writes -> C-reads

        // ---- c: fused STDP w-update + matvec (bit-exact order: c=0..7, xyzw) ----
        // Do not refactor into FMA (rounding would drift w, can flip spikes).
        const float zi_own = z;        // own neuron's spike
        const float tpoi   = tpo_own;  // own neuron's post-trace
        xk = x_s[(k + 1) * ROWS_PER_BLOCK + wv];   // prefetch next input
        float acc = 0.0f;
        const float4* z4s  = (const float4*)z_s;
        const float4* tp4s = (const float4*)tp_s;
        #pragma unroll
        for (int c = 0; c < CHUNKS; ++c) {
            const int slot = c * 32 + perm_base;   // split-slot permutation
            float4 zj = z4s[slot];
            float4 tj = tp4s[slot];
            float nw;
            nw = wreg[c].x + (ETA * (zi_own * tj.x) - ETA * (tpoi * zj.x));
            nw = fminf(fmaxf(nw, 0.0f), 1.0f); wreg[c].x = nw; acc += nw * zj.x;
            nw = wreg[c].y + (ETA * (zi_own * tj.y) - ETA * (tpoi * zj.y));
            nw = fminf(fmaxf(nw, 0.0f), 1.0f); wreg[c].y = nw; acc += nw * zj.y;
            nw = wreg[c].z + (ETA * (zi_own * tj.z) - ETA * (tpoi * zj.z));
            nw = fminf(fmaxf(nw, 0.0f), 1.0f); wreg[c].z = nw; acc += nw * zj.z;
            nw = wreg[c].w + (ETA * (zi_own * tj.w) - ETA * (tpoi * zj.w));
            nw = fminf(fmaxf(nw, 0.0f), 1.0f); wreg[c].w = nw; acc += nw * zj.w;
        }
        #pragma unroll
        for (int m = 32; m >= 1; m >>= 1) acc += __shfl_xor(acc, m, 64);
        isyn = acc;                    // i_syn for step k+1, in registers

        __syncthreads();               // WAR: C-reads -> next b-writes
    }
}

extern "C" void kernel_launch(void* const* d_in, const int* in_sizes, int n_in,
                              void* d_out, int out_size, void* d_ws, size_t ws_size,
                              hipStream_t stream) {
    const float* x     = (const float*)d_in[0];   // [T,N]
    const float* w_in  = (const float*)d_in[1];   // [N,N]
    const float* tpre  = (const float*)d_in[2];   // [N]
    const float* tpost = (const float*)d_in[3];   // [N]
    float*       out   = (float*)d_out;           // [T,N]

    unsigned long long* zpub = (unsigned long long*)d_ws;

    // Pad each published word to its own line if the workspace allows:
    // 128B stride (TCC line) needs 64KB, 64B needs 32KB, else packed (4KB).
    int stride;
    if      (ws_size >= (size_t)2 * BLOCKS * 16 * sizeof(unsigned long long)) stride = 16;
    else if (ws_size >= (size_t)2 * BLOCKS *  8 * sizeof(unsigned long long)) stride = 8;
    else                                                                      stride = 1;

    void* args[] = {(void*)&x, (void*)&w_in, (void*)&tpre, (void*)&tpost,
                    (void*)&zpub, (void*)&stride, (void*)&out};
    hipLaunchCooperativeKernel((void*)snn_msg_kernel,
                               dim3(BLOCKS), dim3(THREADS),
                               args, 0, stream);
}